// Round 14
// baseline (171.979 us; speedup 1.0000x reference)
//
#include <hip/hip_runtime.h>
#include <cstdint>

#define HB 8
#define CM 128
#define NHEAD 8
#define NPT 8
#define DHD 16
#define HS 64
#define WS 64
#define LTOT 4096
#define NQA 192   // fused off(128) + attn(64)
#define QAP 196   // qaT LDS pitch (floats): 196%32=4 -> rows shift banks
#define LFP 132   // gemm_val transpose pitch

typedef float floatx4 __attribute__((ext_vector_type(4)));
typedef short bf16x8 __attribute__((ext_vector_type(8)));

__device__ __forceinline__ unsigned short f2bf_rne(float x) {
  unsigned u = __float_as_uint(x);
  return (unsigned short)((u + 0x7FFFu + ((u >> 16) & 1)) >> 16);
}
__device__ __forceinline__ unsigned pack_bf2(float a, float b) {
  return ((unsigned)f2bf_rne(b) << 16) | f2bf_rne(a);
}
__device__ __forceinline__ void split_bf(float x, unsigned short& h, unsigned short& l) {
  unsigned u = __float_as_uint(x);
  h = (unsigned short)(u >> 16);
  float r = x - __uint_as_float(u & 0xFFFF0000u);
  l = (unsigned short)(__float_as_uint(r) >> 16);
}
__device__ __forceinline__ float fast_tanh(float x) {
  float e = __expf(2.0f * x);
  return 1.0f - 2.0f / (e + 1.0f);
}

// Weight prep -> bf16 hi/lo fragment layout: element (n,k) at (k>>3)*Nn*8 + n*8 + (k&7).
__global__ __launch_bounds__(256) void prep(const float* __restrict__ Wv,
                                            const float* __restrict__ Wo,
                                            const float* __restrict__ Wa,
                                            const float* __restrict__ Ww,
                                            const float* __restrict__ bo,
                                            const float* __restrict__ ba,
                                            unsigned short* __restrict__ wf_val,
                                            unsigned short* __restrict__ wf_qa,
                                            unsigned short* __restrict__ wf_out,
                                            float* __restrict__ bias_qa) {
  const int gid = blockIdx.x * 256 + threadIdx.x;  // 14336 = 32 k4 * 448 n
  const int k4 = gid / 448;
  const int ng = gid - k4 * 448;

  const float* src;
  unsigned short* dst;
  int Nsrc, Nn, nd, n;
  if (ng < 128) {        src = Wv; dst = wf_val; Nsrc = 128; Nn = 128; n = ng;        nd = n; }
  else if (ng < 256) {   src = Wo; dst = wf_qa;  Nsrc = 128; Nn = 192; n = ng - 128;  nd = n; }
  else if (ng < 320) {   src = Wa; dst = wf_qa;  Nsrc = 64;  Nn = 192; n = ng - 256;  nd = n + 128; }
  else {                 src = Ww; dst = wf_out; Nsrc = 128; Nn = 128; n = ng - 320;  nd = n; }

  ushort4 hi, lo;
  split_bf(src[(k4 * 4 + 0) * Nsrc + n], hi.x, lo.x);
  split_bf(src[(k4 * 4 + 1) * Nsrc + n], hi.y, lo.y);
  split_bf(src[(k4 * 4 + 2) * Nsrc + n], hi.z, lo.z);
  split_bf(src[(k4 * 4 + 3) * Nsrc + n], hi.w, lo.w);
  const int off = (k4 >> 1) * Nn * 8 + nd * 8 + (k4 & 1) * 4;
  *(ushort4*)(dst + off) = hi;
  *(ushort4*)(dst + Nn * 128 + off) = lo;

  if (gid < 128) bias_qa[gid] = bo[gid];
  else if (gid < 192) bias_qa[gid] = ba[gid - 128];
}

// K1: value projection (R12-validated: coalesced LDS-transpose epilogue).
__global__ __launch_bounds__(256, 4) void gemm_val(const float* __restrict__ nbr,
                                                   const unsigned short* __restrict__ WF,
                                                   const float* __restrict__ bias,
                                                   unsigned short* __restrict__ value) {
  __shared__ char smem[33792];
  unsigned short* AB = (unsigned short*)smem;  // hi [64][128]; lo at +8192 us
  const int t = threadIdx.x;
  const int ml0 = blockIdx.x * 64;
  const int b = blockIdx.y;

  {
    const float* src = nbr + (size_t)b * CM * LTOT + ml0;
    const int x = t & 63, kq = t >> 6;
#pragma unroll
    for (int i = 0; i < 8; i++) {
      const int kb = kq * 4 + i * 16;
      ushort4 hi, lo;
      split_bf(src[(size_t)(kb + 0) * LTOT + x], hi.x, lo.x);
      split_bf(src[(size_t)(kb + 1) * LTOT + x], hi.y, lo.y);
      split_bf(src[(size_t)(kb + 2) * LTOT + x], hi.z, lo.z);
      split_bf(src[(size_t)(kb + 3) * LTOT + x], hi.w, lo.w);
      const int off = x * 128 + (((kb >> 3) ^ (x & 15)) << 3) + (kb & 7);
      *(ushort4*)(AB + off) = hi;
      *(ushort4*)(AB + 8192 + off) = lo;
    }
  }
  __syncthreads();

  const int w = t >> 6, lane = t & 63;
  const int wm = (w >> 1) * 32, wn = (w & 1) * 64;
  const int nl = lane & 15, q = lane >> 4;

  floatx4 acc[2][4];
#pragma unroll
  for (int mt = 0; mt < 2; mt++)
#pragma unroll
    for (int j = 0; j < 4; j++) acc[mt][j] = {0.0f, 0.0f, 0.0f, 0.0f};

#pragma unroll
  for (int K0 = 0; K0 < 4; K0++) {
    bf16x8 ah[2], al[2];
#pragma unroll
    for (int mt = 0; mt < 2; mt++) {
      const int m = wm + mt * 16 + nl;
      const int off = m * 128 + (((K0 * 4 + q) ^ (m & 15)) << 3);
      ah[mt] = *(bf16x8*)(AB + off);
      al[mt] = *(bf16x8*)(AB + 8192 + off);
    }
#pragma unroll
    for (int j = 0; j < 4; j++) {
      const size_t o = (size_t)(K0 * 4 + q) * CM * 8 + (wn + j * 16 + nl) * 8;
      const bf16x8 wh = *(const bf16x8*)(WF + o);
      const bf16x8 wl = *(const bf16x8*)(WF + (size_t)CM * 128 + o);
#pragma unroll
      for (int mt = 0; mt < 2; mt++) {
        acc[mt][j] = __builtin_amdgcn_mfma_f32_16x16x32_bf16(al[mt], wh, acc[mt][j], 0, 0, 0);
        acc[mt][j] = __builtin_amdgcn_mfma_f32_16x16x32_bf16(ah[mt], wl, acc[mt][j], 0, 0, 0);
        acc[mt][j] = __builtin_amdgcn_mfma_f32_16x16x32_bf16(ah[mt], wh, acc[mt][j], 0, 0, 0);
      }
    }
  }

  __syncthreads();  // AB dead
  float* LF = (float*)smem;
#pragma unroll
  for (int j = 0; j < 4; j++) {
    const int gc = wn + j * 16 + nl;
    const float bv = bias[gc];
#pragma unroll
    for (int mt = 0; mt < 2; mt++)
#pragma unroll
      for (int r = 0; r < 4; r++)
        LF[(wm + mt * 16 + q * 4 + r) * LFP + gc] = acc[mt][j][r] + bv;
  }
  __syncthreads();
#pragma unroll
  for (int i = 0; i < 4; i++) {
    const int c = t + i * 256;
    const int h = c >> 7, rem = c & 127, l = rem >> 1, half = rem & 1;
    const float* sp = LF + l * LFP + h * 16 + half * 8;
    uint4 st;
    st.x = pack_bf2(sp[0], sp[1]);
    st.y = pack_bf2(sp[2], sp[3]);
    st.z = pack_bf2(sp[4], sp[5]);
    st.w = pack_bf2(sp[6], sp[7]);
    *(uint4*)(value + ((size_t)(b * NHEAD + h) * LTOT + ml0 + l) * DHD + half * 8) = st;
  }
}

// K2: stage ext -> qa GEMM (LDS) -> params (full corner WEIGHTS computed once,
// exact masked-factor form: w_c = aw * sx_c * sy_c with sx/sy zeroed per-corner
// validity — true fx/fy retained for valid corners) -> d2-pair gather (uint4
// loads, zero weight VALU) -> out GEMM. 49152 B LDS, 3 blocks/CU.
__global__ __launch_bounds__(256, 3) void samp(const float* __restrict__ ext,
                                               const unsigned short* __restrict__ value,
                                               const unsigned short* __restrict__ wf_qa,
                                               const unsigned short* __restrict__ wf_out,
                                               const float* __restrict__ bias_qa,
                                               const float* __restrict__ b_out,
                                               float* __restrict__ out) {
  __shared__ char smem[49152];
  // phase A/B: AB staging [0,16384); qaT [8192,33280) (AB dead before qaT stores)
  unsigned short* AB = (unsigned short*)smem;        // [32][128] hi; lo at +4096 us
  float* qaT = (float*)(smem + 8192);                // [32][QAP]
  // phase C/D: W4 [0,32768), BAD [32768,40960), FR [40960,49152)
  float4* W4 = (float4*)smem;                        // [8 p][256 lh] corner weights
  unsigned* BAD = (unsigned*)(smem + 32768);         // base | dx<<12 | dy<<13
  unsigned short* FR = (unsigned short*)(smem + 40960);

  const int t = threadIdx.x;
  const int b = blockIdx.x & 7;                      // XCD affinity
  const int ml0 = (blockIdx.x >> 3) * 32;
  const int w = t >> 6, lane = t & 63;
  const int nl = lane & 15, q = lane >> 4;

  // ---- stage ext 32-l tile (fp32 -> bf16 hi/lo, swizzled) ----
  {
    const float* src = ext + (size_t)b * CM * LTOT + ml0;
    const int x = t & 31, kq = t >> 5;
#pragma unroll
    for (int i = 0; i < 4; i++) {
      const int kb = i * 32 + kq * 4;
      ushort4 hi, lo;
      split_bf(src[(size_t)(kb + 0) * LTOT + x], hi.x, lo.x);
      split_bf(src[(size_t)(kb + 1) * LTOT + x], hi.y, lo.y);
      split_bf(src[(size_t)(kb + 2) * LTOT + x], hi.z, lo.z);
      split_bf(src[(size_t)(kb + 3) * LTOT + x], hi.w, lo.w);
      const int off = x * 128 + (((kb >> 3) ^ (x & 15)) << 3) + (kb & 7);
      *(ushort4*)(AB + off) = hi;
      *(ushort4*)(AB + 4096 + off) = lo;
    }
  }
  __syncthreads();

  // ---- qa GEMM: 32m x 192n, 4 waves, wave = 16m x 96n ----
  {
    const int wm = (w & 1) * 16;
    const int wn = (w >> 1) * 96;
    floatx4 acc[6];
#pragma unroll
    for (int j = 0; j < 6; j++) acc[j] = {0.0f, 0.0f, 0.0f, 0.0f};
#pragma unroll
    for (int K0 = 0; K0 < 4; K0++) {
      const int m = wm + nl;
      const int off = m * 128 + (((K0 * 4 + q) ^ (m & 15)) << 3);
      const bf16x8 ah = *(bf16x8*)(AB + off);
      const bf16x8 al = *(bf16x8*)(AB + 4096 + off);
#pragma unroll
      for (int j = 0; j < 6; j++) {
        const size_t o = (size_t)(K0 * 4 + q) * NQA * 8 + (wn + j * 16 + nl) * 8;
        const bf16x8 wh = *(const bf16x8*)(wf_qa + o);
        const bf16x8 wl = *(const bf16x8*)(wf_qa + (size_t)NQA * 128 + o);
        acc[j] = __builtin_amdgcn_mfma_f32_16x16x32_bf16(al, wh, acc[j], 0, 0, 0);
        acc[j] = __builtin_amdgcn_mfma_f32_16x16x32_bf16(ah, wl, acc[j], 0, 0, 0);
        acc[j] = __builtin_amdgcn_mfma_f32_16x16x32_bf16(ah, wh, acc[j], 0, 0, 0);
      }
    }
    __syncthreads();  // AB fully read -> qaT may overwrite [8192,16384)
#pragma unroll
    for (int j = 0; j < 6; j++) {
      const int n = wn + j * 16 + nl;
      const float bv = bias_qa[n];
#pragma unroll
      for (int r = 0; r < 4; r++)
        qaT[(wm + q * 4 + r) * QAP + n] = acc[j][r] + bv;
    }
  }
  __syncthreads();

  // ---- params: thread = (ll = t>>3, h = t&7); full corner weights once ----
  {
    const int ll = t >> 3, h = t & 7;
    const float* qrow = qaT + ll * QAP;
    float4 of[4];
#pragma unroll
    for (int j = 0; j < 4; j++) of[j] = *(const float4*)(qrow + h * 16 + j * 4);
    const float4 lga = *(const float4*)(qrow + 128 + h * 8);
    const float4 lgb = *(const float4*)(qrow + 128 + h * 8 + 4);
    __syncthreads();  // qaT dead -> W4/BAD may overwrite
    const float lg[8] = {lga.x, lga.y, lga.z, lga.w, lgb.x, lgb.y, lgb.z, lgb.w};
    float m = lg[0];
#pragma unroll
    for (int p = 1; p < 8; p++) m = fmaxf(m, lg[p]);
    float e[8], s = 0.0f;
#pragma unroll
    for (int p = 0; p < 8; p++) { e[p] = __expf(lg[p] - m); s += e[p]; }
    const float inv = 1.0f / s;
    const int l = ml0 + ll;
    const float xf = (float)(l & (WS - 1));
    const float yf = (float)(l >> 6);
#pragma unroll
    for (int p = 0; p < 8; p++) {
      const float ox = (p & 1) ? of[p >> 1].z : of[p >> 1].x;
      const float oy = (p & 1) ? of[p >> 1].w : of[p >> 1].y;
      const float aw = e[p] * inv;
      const float px = xf + 10.0f * fast_tanh(ox);
      const float py = yf + 10.0f * fast_tanh(oy);
      const float x0f = floorf(px), y0f = floorf(py);
      const float fx = px - x0f, fy = py - y0f;
      const int ix = (int)x0f, iy = (int)y0f;
      // masked axis factors: zero per-corner validity, TRUE fx/fy for valid corners
      const float sx0 = ((unsigned)ix < WS) ? (1.0f - fx) : 0.0f;
      const float sx1 = ((unsigned)(ix + 1) < WS) ? fx : 0.0f;
      const float sy0 = ((unsigned)iy < HS) ? (1.0f - fy) : 0.0f;
      const float sy1 = ((unsigned)(iy + 1) < HS) ? fy : 0.0f;
      const int x0c = min(max(ix, 0), WS - 1);
      const int y0c = min(max(iy, 0), HS - 1);
      const int dx = min(max(ix + 1, 0), WS - 1) - x0c;
      const int dy = min(max(iy + 1, 0), HS - 1) - y0c;
      const int idx = p * 256 + t;
      W4[idx] = {aw * sx0 * sy0, aw * sx1 * sy0, aw * sx0 * sy1, aw * sx1 * sy1};
      BAD[idx] = (unsigned)((y0c << 6) + x0c) | ((unsigned)dx << 12) | ((unsigned)dy << 13);
    }
  }
  __syncthreads();

  // ---- gather: thread = (uu=(ll,h), d2); 2 passes; 16 B uint4 bf16 loads ----
  {
    const int d2 = t & 1;
    const int u = t >> 1;  // 0..127
#pragma unroll
    for (int ps = 0; ps < 2; ps++) {
      const int uu = ps * 128 + u;
      const int ll = uu >> 3;
      const int h = uu & 7;
      const unsigned short* vbb = value + ((size_t)(b * NHEAD + h) * LTOT) * DHD + d2 * 8;

      float o[8];
#pragma unroll
      for (int j = 0; j < 8; j++) o[j] = 0.0f;

#pragma unroll
      for (int p = 0; p < 8; p++) {
        const int idx = p * 256 + uu;
        const float4 wv = W4[idx];   // w00, w10, w01, w11
        const unsigned ub = BAD[idx];
        const int base = ub & 0xFFF;
        const int ddx = (ub >> 12) & 1;
        const int o2b = base + (((ub >> 13) & 1) << 6);
        const uint4 r0 = *(const uint4*)(vbb + (size_t)base * DHD);
        const uint4 r1 = *(const uint4*)(vbb + (size_t)(base + ddx) * DHD);
        const uint4 r2 = *(const uint4*)(vbb + (size_t)o2b * DHD);
        const uint4 r3 = *(const uint4*)(vbb + (size_t)(o2b + ddx) * DHD);
#pragma unroll
        for (int j = 0; j < 4; j++) {
          const unsigned c0 = (&r0.x)[j], c1 = (&r1.x)[j], c2 = (&r2.x)[j], c3 = (&r3.x)[j];
          o[j * 2 + 0] += wv.x * __uint_as_float(c0 << 16) + wv.y * __uint_as_float(c1 << 16) +
                          wv.z * __uint_as_float(c2 << 16) + wv.w * __uint_as_float(c3 << 16);
          o[j * 2 + 1] += wv.x * __uint_as_float(c0 & 0xFFFF0000u) + wv.y * __uint_as_float(c1 & 0xFFFF0000u) +
                          wv.z * __uint_as_float(c2 & 0xFFFF0000u) + wv.w * __uint_as_float(c3 & 0xFFFF0000u);
        }
      }
      // frag chunk kc = h*2+d2 covers k = h*16 + d2*8 + (0..7)
      const int off = ll * 128 + (((h * 2 + d2) ^ (ll & 15)) << 3);
      uint4 st;
      st.x = pack_bf2(o[0], o[1]);
      st.y = pack_bf2(o[2], o[3]);
      st.z = pack_bf2(o[4], o[5]);
      st.w = pack_bf2(o[6], o[7]);
      *(uint4*)(FR + off) = st;
    }
  }
  __syncthreads();

  // ---- out GEMM: 32m x 128n, 4 waves, wave = 16m x 64n; direct float4 stores ----
  {
    const int wm = (w & 1) * 16;
    const int wn = (w >> 1) * 64;
    floatx4 acc[4];
#pragma unroll
    for (int j = 0; j < 4; j++) acc[j] = {0.0f, 0.0f, 0.0f, 0.0f};
#pragma unroll
    for (int K0 = 0; K0 < 4; K0++) {
      const int m = wm + nl;
      const int off = m * 128 + (((K0 * 4 + q) ^ (m & 15)) << 3);
      const bf16x8 ah = *(bf16x8*)(FR + off);
#pragma unroll
      for (int j = 0; j < 4; j++) {
        const int n = wn + j * 16 + nl;
        const size_t o = (size_t)(K0 * 4 + q) * CM * 8 + n * 8;
        const bf16x8 wh = *(const bf16x8*)(wf_out + o);
        const bf16x8 wl = *(const bf16x8*)(wf_out + (size_t)CM * 128 + o);
        acc[j] = __builtin_amdgcn_mfma_f32_16x16x32_bf16(ah, wl, acc[j], 0, 0, 0);
        acc[j] = __builtin_amdgcn_mfma_f32_16x16x32_bf16(ah, wh, acc[j], 0, 0, 0);
      }
    }
#pragma unroll
    for (int j = 0; j < 4; j++) {
      const int gc = wn + j * 16 + nl;
      const float bv = b_out[gc];
      float4 st = {acc[j][0] + bv, acc[j][1] + bv, acc[j][2] + bv, acc[j][3] + bv};
      *(float4*)(out + ((size_t)b * CM + gc) * LTOT + ml0 + wm + q * 4) = st;
    }
  }
}

extern "C" void kernel_launch(void* const* d_in, const int* in_sizes, int n_in,
                              void* d_out, int out_size, void* d_ws, size_t ws_size,
                              hipStream_t stream) {
  const float* nbr    = (const float*)d_in[0];
  const float* ext    = (const float*)d_in[1];
  const float* W_val  = (const float*)d_in[2];
  const float* b_val  = (const float*)d_in[3];
  const float* W_off  = (const float*)d_in[4];
  const float* b_off  = (const float*)d_in[5];
  const float* W_attn = (const float*)d_in[6];
  const float* b_attn = (const float*)d_in[7];
  const float* W_out  = (const float*)d_in[8];
  const float* b_out  = (const float*)d_in[9];
  float* out = (float*)d_out;

  unsigned short* value = (unsigned short*)d_ws;             // 8.39 MB bf16 [b][h][l][16]
  unsigned short* wf_val = value + (size_t)HB * NHEAD * LTOT * DHD;  // 64 KB
  unsigned short* wf_qa  = wf_val + 128 * 128 * 2;           // 96 KB
  unsigned short* wf_out = wf_qa + 192 * 128 * 2;            // 64 KB
  float* bias_qa = (float*)(wf_out + 128 * 128 * 2);         // 768 B

  prep<<<56, 256, 0, stream>>>(W_val, W_off, W_attn, W_out, b_off, b_attn,
                               wf_val, wf_qa, wf_out, bias_qa);
  gemm_val<<<dim3(64, HB), 256, 0, stream>>>(nbr, wf_val, b_val, value);
  samp<<<dim3(128 * HB), 256, 0, stream>>>(ext, value, wf_qa, wf_out, bias_qa, b_out, out);
}